// Round 1
// baseline (364.057 us; speedup 1.0000x reference)
//
#include <hip/hip_runtime.h>

#define GRIDSZ 14
#define PATCH  16
#define H      224
#define W      224
#define B      32
#define C      96

// ws layout:
//   [0, 8192) floats            : norm sums per (b, pi, pj)   (32*16*16)
//   [32768, 32768+256) bytes    : int2 shifts[32]

__global__ void zero_norms_kernel(float* __restrict__ nbuf) {
    int i = blockIdx.x * blockDim.x + threadIdx.x;  // 8192 threads exactly
    nbuf[i] = 0.0f;
}

// grid: 32 * 16 * 4 = 2048 blocks, 256 threads (4 waves).
// Block handles (b, pi, slice): 336 rows, each wave 84 rows, lane<56 loads float4.
__global__ void norms_kernel(const float* __restrict__ x, float* __restrict__ nbuf) {
    int bi    = blockIdx.x;
    int slice = bi & 3;
    int pi    = (bi >> 2) & 15;
    int b     = bi >> 6;
    int wave  = threadIdx.x >> 6;
    int lane  = threadIdx.x & 63;

    __shared__ float bins[16];
    if (threadIdx.x < 16) bins[threadIdx.x] = 0.0f;
    __syncthreads();

    float a0 = 0.f, a1 = 0.f, a2 = 0.f, a3 = 0.f;
    if (lane < 56) {
        const size_t batchOff = (size_t)b * C * H * W;
        // j = slice*336 + it*4 + wave ; c = j/14 ; gi = j%14  (336 = 24*14)
        int c  = slice * 24;
        int gi = wave;            // wave in [0,4) < 14
        for (int it = 0; it < 84; ++it) {
            int h = gi * PATCH + pi;
            const float4* row = (const float4*)(x + batchOff + ((size_t)c * H + h) * W);
            float4 v = row[lane];
            a0 += v.x * v.x;
            a1 += v.y * v.y;
            a2 += v.z * v.z;
            a3 += v.w * v.w;
            gi += 4;
            if (gi >= 14) { gi -= 14; c += 1; }
        }
        int base = (lane & 3) << 2;   // pj of v.x = (4*lane)%16
        atomicAdd(&bins[base + 0], a0);
        atomicAdd(&bins[base + 1], a1);
        atomicAdd(&bins[base + 2], a2);
        atomicAdd(&bins[base + 3], a3);
    }
    __syncthreads();
    if (threadIdx.x < 16)
        atomicAdd(&nbuf[(b * 16 + pi) * 16 + threadIdx.x], bins[threadIdx.x]);
}

// 32 blocks x 64 threads. First-occurrence argmax over 256 bins per batch.
__global__ void argmax_kernel(const float* __restrict__ nbuf, int2* __restrict__ shifts) {
    int b = blockIdx.x;
    int t = threadIdx.x;
    float v = -1.0f;
    int idx = 0;
    for (int r = 0; r < 4; ++r) {
        int i = r * 64 + t;                 // increasing idx per thread
        float u = nbuf[b * 256 + i];
        if (u > v) { v = u; idx = i; }      // strict > keeps first occurrence
    }
    for (int off = 32; off > 0; off >>= 1) {
        float ov = __shfl_down(v, off);
        int   oi = __shfl_down(idx, off);
        if (ov > v || (ov == v && oi < idx)) { v = ov; idx = oi; }
    }
    if (t == 0) shifts[b] = make_int2(idx >> 4, idx & 15);   // (si, sj)
}

// grid: 32 * 672 blocks, 256 threads. Each block: 32 rows of one batch,
// wave-per-row (8 iterations). Row staged in per-wave LDS, read back rotated.
__global__ void roll_kernel(const float* __restrict__ x, float* __restrict__ out,
                            const int2* __restrict__ shifts) {
    int blk   = blockIdx.x;
    int b     = blk / 672;
    int chunk = blk % 672;
    int wave  = threadIdx.x >> 6;
    int lane  = threadIdx.x & 63;

    int2 s = shifts[b];
    int si = s.x, sj = s.y;

    __shared__ __align__(16) float buf[4][224];
    const size_t batchOff = (size_t)b * C * H * W;

    for (int it = 0; it < 8; ++it) {
        int rowInBatch = chunk * 32 + it * 4 + wave;   // in [0, 96*224)
        int c = rowInBatch / H;
        int h = rowInBatch - c * H;
        int sh = h + si; if (sh >= H) sh -= H;

        const float4* src = (const float4*)(x + batchOff + ((size_t)c * H + sh) * W);
        if (lane < 56) {
            float4 v = src[lane];
            *(float4*)&buf[wave][lane * 4] = v;
        }
        __syncthreads();
        if (lane < 56) {
            int w0 = lane * 4 + sj;                    // max 235
            int i0 = w0;     if (i0 >= W) i0 -= W;
            int i1 = w0 + 1; if (i1 >= W) i1 -= W;
            int i2 = w0 + 2; if (i2 >= W) i2 -= W;
            int i3 = w0 + 3; if (i3 >= W) i3 -= W;
            float4 o;
            o.x = buf[wave][i0];
            o.y = buf[wave][i1];
            o.z = buf[wave][i2];
            o.w = buf[wave][i3];
            float4* dst = (float4*)(out + batchOff + (size_t)rowInBatch * W);
            dst[lane] = o;
        }
        __syncthreads();
    }
}

extern "C" void kernel_launch(void* const* d_in, const int* in_sizes, int n_in,
                              void* d_out, int out_size, void* d_ws, size_t ws_size,
                              hipStream_t stream) {
    const float* x = (const float*)d_in[0];
    float* outp = (float*)d_out;
    float* nbuf = (float*)d_ws;
    int2* shifts = (int2*)((char*)d_ws + 8192 * sizeof(float));

    zero_norms_kernel<<<32, 256, 0, stream>>>(nbuf);
    norms_kernel<<<2048, 256, 0, stream>>>(x, nbuf);
    argmax_kernel<<<32, 64, 0, stream>>>(nbuf, shifts);
    roll_kernel<<<21504, 256, 0, stream>>>(x, outp, shifts);
}

// Round 2
// 353.159 us; speedup vs baseline: 1.0309x; 1.0309x over previous
//
#include <hip/hip_runtime.h>

#define H 224
#define W 224
#define B 32
#define C 96

// ws layout (direct mode): nbuf[slice][b][pi][pj] = 4*32*16*16 floats (128 KiB),
//                          int2 shifts[32] at +128 KiB
// ws layout (atomic mode): nbuf[b][pi][pj] = 8192 floats (32 KiB), shifts at +32 KiB

__global__ void zero_norms_kernel(float* __restrict__ nbuf) {
    int i = blockIdx.x * blockDim.x + threadIdx.x;  // 8192 threads exactly
    nbuf[i] = 0.0f;
}

// grid: dim3(64, 32) -> blockIdx.x = pi*4 + slice, blockIdx.y = b. 256 threads.
// Block covers 24 channels (slice) for one (b, pi): 336 rows. Each wave runs
// TWO row streams (c and c+12) off one address chain -> 2 loads in flight/iter.
template<int DIRECT>
__global__ void norms_kernel(const float* __restrict__ x, float* __restrict__ nbuf) {
    int pi    = blockIdx.x >> 2;
    int slice = blockIdx.x & 3;
    int b     = blockIdx.y;
    int wave  = threadIdx.x >> 6;
    int lane  = threadIdx.x & 63;

    __shared__ float bins[16];
    if (threadIdx.x < 16) bins[threadIdx.x] = 0.0f;
    __syncthreads();

    if (lane < 56) {
        const float* base = x + (size_t)b * C * H * W;
        int c  = slice * 24;      // stream A: c..c+11 ; stream B: +12
        int gi = wave;
        float a0=0.f,a1=0.f,a2=0.f,a3=0.f;
        float b0=0.f,b1=0.f,b2=0.f,b3=0.f;
        #pragma unroll 2
        for (int it = 0; it < 42; ++it) {
            const float4* rowA = (const float4*)(base + ((size_t)c * H + gi * 16 + pi) * W);
            const float4* rowB = rowA + (size_t)12 * H * W / 4;
            float4 va = rowA[lane];
            float4 vb = rowB[lane];
            a0 += va.x * va.x; a1 += va.y * va.y; a2 += va.z * va.z; a3 += va.w * va.w;
            b0 += vb.x * vb.x; b1 += vb.y * vb.y; b2 += vb.z * vb.z; b3 += vb.w * vb.w;
            gi += 4; if (gi >= 14) { gi -= 14; c += 1; }
        }
        a0 += b0; a1 += b1; a2 += b2; a3 += b3;
        int bse = (lane & 3) << 2;            // pj of v.x = (4*lane)%16
        atomicAdd(&bins[bse + 0], a0);
        atomicAdd(&bins[bse + 1], a1);
        atomicAdd(&bins[bse + 2], a2);
        atomicAdd(&bins[bse + 3], a3);
    }
    __syncthreads();
    if (threadIdx.x < 16) {
        if (DIRECT)
            nbuf[((slice * B + b) * 16 + pi) * 16 + threadIdx.x] = bins[threadIdx.x];
        else
            atomicAdd(&nbuf[(b * 16 + pi) * 16 + threadIdx.x], bins[threadIdx.x]);
    }
}

// 32 blocks x 64 threads. First-occurrence argmax over 256 bins per batch.
template<int DIRECT>
__global__ void argmax_kernel(const float* __restrict__ nbuf, int2* __restrict__ shifts) {
    int b = blockIdx.x;
    int t = threadIdx.x;
    float v = -1.0f;
    int idx = 0;
    for (int r = 0; r < 4; ++r) {
        int i = r * 64 + t;                 // increasing idx per thread
        float u;
        if (DIRECT) {
            int o = b * 256 + i;
            u = nbuf[o] + nbuf[8192 + o] + nbuf[16384 + o] + nbuf[24576 + o];
        } else {
            u = nbuf[b * 256 + i];
        }
        if (u > v) { v = u; idx = i; }      // strict > keeps first occurrence
    }
    for (int off = 32; off > 0; off >>= 1) {
        float ov = __shfl_down(v, off);
        int   oi = __shfl_down(idx, off);
        if (ov > v || (ov == v && oi < idx)) { v = ov; idx = oi; }
    }
    if (t == 0) shifts[b] = make_int2(idx >> 4, idx & 15);   // (si, sj)
}

// Rotate one wave's 8 rows with no LDS / no barriers.
// sj = 4q + R: lane l loads aligned vec (l+q)%56; sub-vec shift R taken from
// lane l+1's vec via __shfl. R is a compile-time template param (uniform/batch).
template<int R>
__device__ __forceinline__ void roll_body(const float* __restrict__ xb,
                                          float* __restrict__ ob,
                                          int c0, int h0, int sh0,
                                          int q, int lane) {
    int v = lane + q;  if (v >= 56) v -= 56;
    int nl = lane + 1; if (nl >= 56) nl = 0;
    int sh = sh0;
    #pragma unroll
    for (int it = 0; it < 8; ++it) {
        int h = h0 + it * 4;                       // stays < 224 within a block
        const float4* srow = (const float4*)(xb + ((size_t)c0 * H + sh) * W);
        float4*       drow = (float4*)      (ob + ((size_t)c0 * H + h)  * W);
        float4 a = srow[v];
        float4 o;
        if (R == 0) {
            o = a;
        } else {
            float nx = __shfl(a.x, nl);
            float ny = (R >= 2) ? __shfl(a.y, nl) : 0.0f;
            float nz = (R == 3) ? __shfl(a.z, nl) : 0.0f;
            if (R == 1) { o.x = a.y; o.y = a.z; o.z = a.w; o.w = nx; }
            if (R == 2) { o.x = a.z; o.y = a.w; o.z = nx;  o.w = ny; }
            if (R == 3) { o.x = a.w; o.y = nx;  o.z = ny;  o.w = nz; }
        }
        drow[lane] = o;
        sh += 4; if (sh >= H) sh -= H;
    }
}

// grid: dim3(672, 32) -> blockIdx.x = chunk (32 rows), blockIdx.y = b. 256 threads.
// Wave w handles rows h = (chunk%7)*32 + w + 4*it, channel c = chunk/7.
__global__ void roll_kernel(const float* __restrict__ x, float* __restrict__ out,
                            const int2* __restrict__ shifts) {
    int b     = blockIdx.y;
    int chunk = blockIdx.x;
    int wave  = threadIdx.x >> 6;
    int lane  = threadIdx.x & 63;
    if (lane >= 56) return;

    int2 s = shifts[b];
    int si = s.x, sj = s.y;
    int q = sj >> 2, r = sj & 3;

    int c0 = chunk / 7;
    int h0 = (chunk % 7) * 32 + wave;
    int sh0 = h0 + si; if (sh0 >= H) sh0 -= H;

    const float* xb = x   + (size_t)b * C * H * W;
    float*       ob = out + (size_t)b * C * H * W;

    switch (r) {
        case 0: roll_body<0>(xb, ob, c0, h0, sh0, q, lane); break;
        case 1: roll_body<1>(xb, ob, c0, h0, sh0, q, lane); break;
        case 2: roll_body<2>(xb, ob, c0, h0, sh0, q, lane); break;
        default: roll_body<3>(xb, ob, c0, h0, sh0, q, lane); break;
    }
}

extern "C" void kernel_launch(void* const* d_in, const int* in_sizes, int n_in,
                              void* d_out, int out_size, void* d_ws, size_t ws_size,
                              hipStream_t stream) {
    const float* x = (const float*)d_in[0];
    float* outp = (float*)d_out;

    const size_t directBytes = (size_t)4 * B * 256 * sizeof(float);  // 128 KiB
    if (ws_size >= directBytes + 256) {
        float* nbuf  = (float*)d_ws;
        int2* shifts = (int2*)((char*)d_ws + directBytes);
        norms_kernel<1><<<dim3(64, 32), 256, 0, stream>>>(x, nbuf);
        argmax_kernel<1><<<32, 64, 0, stream>>>(nbuf, shifts);
        roll_kernel<<<dim3(672, 32), 256, 0, stream>>>(x, outp, shifts);
    } else {
        float* nbuf  = (float*)d_ws;
        int2* shifts = (int2*)((char*)d_ws + 8192 * sizeof(float));
        zero_norms_kernel<<<32, 256, 0, stream>>>(nbuf);
        norms_kernel<0><<<dim3(64, 32), 256, 0, stream>>>(x, nbuf);
        argmax_kernel<0><<<32, 64, 0, stream>>>(nbuf, shifts);
        roll_kernel<<<dim3(672, 32), 256, 0, stream>>>(x, outp, shifts);
    }
}